// Round 5
// baseline (125.369 us; speedup 1.0000x reference)
//
#include <hip/hip_runtime.h>

// SoftProjection: B=4, N=8192 points, M=4096 queries, F=64 features, K=16 NN.
// R7: no-LDS scan. Evidence R3-R6: instruction trims (R5,-1us) and async DMA
// staging (R6,+2us) both ~neutral; only the occupancy/decoupling fix (R3,
// -15%) moved time. Static floor: scan VALU ~12us + LDS BW ~13us, yet kernel
// ~60us => dominant cost is the ~20 barrier-delimited stage phases (vmcnt(0)
// drain + 16-wave reconvergence, x2 blocks lockstep). pc4 is 128KB/batch =
// fully L2-resident and the scan reads it perfectly coalesced (16B/lane), so
// LDS staging buys nothing. R7 streams both passes directly from L2:
// 4x global_load_dwordx4 per 4-pt group, zero staging, 4 barriers total
// (was ~20). LDS -> ~19KB; SCAP 54->64 (free margin, rank still 64-lane).
// Algorithm/proof unchanged: pass A per-lane min of val = |p|^2 - 2 q.p,
// per-wave radix/ballot 8th-smallest lane-min per half, t = max(halves) =>
// >=16 pts <= t; pass B collects survivors val<=t, exact rank by (val,idx);
// epilogue recomputes exact direct-form d2 for softmax (matches reference).

#define BB 4
#define NN 8192
#define MM 4096
#define FF 64
#define KK 16
#define QPW 4
#define QPB 32
#define SCAP 64
#define NTHR 1024
#define STG 33

__device__ __forceinline__ float min3f(float a, float b, float c) {
    float d;
    asm("v_min3_f32 %0, %1, %2, %3" : "=v"(d) : "v"(a), "v"(b), "v"(c));
    return d;
}

// prep: optional feature transpose (doT) + pc4 = [x,y,z,|p|^2] planes (doPS)
__global__ __launch_bounds__(256) void prep_kernel(const float* __restrict__ pf,
                                                   float* __restrict__ pfT,
                                                   const float* __restrict__ pc,
                                                   float* __restrict__ pc4,
                                                   int doT, int doPS) {
    const int b = blockIdx.y;
    const int n0 = blockIdx.x * 64;
    const int t = threadIdx.x;
    if (doPS && t < 64) {
        int n = n0 + t;
        const float* s = pc + (size_t)b * 3 * NN;
        float x = s[n], y = s[NN + n], z = s[2 * NN + n];
        float ps = fmaf(x, x, fmaf(y, y, z * z));
        float* d = pc4 + (size_t)b * 4 * NN;
        d[n] = x;
        d[NN + n] = y;
        d[2 * NN + n] = z;
        d[3 * NN + n] = ps;
    }
    if (!doT) return;
    __shared__ float tile[64][65];
    const int n = t & 63, fq = t >> 6;
#pragma unroll
    for (int i = 0; i < 16; ++i) {
        int f = fq * 16 + i;
        tile[f][n] = pf[(size_t)b * FF * NN + (size_t)f * NN + n0 + n];
    }
    __syncthreads();
    const int f2 = t & 63, nq = t >> 6;
#pragma unroll
    for (int i = 0; i < 16; ++i) {
        int nn2 = nq * 16 + i;
        pfT[(size_t)b * NN * FF + (size_t)(n0 + nn2) * FF + f2] = tile[f2][nn2];
    }
}

__device__ __forceinline__ unsigned mapf(float f) {
    unsigned u = __float_as_uint(f);
    return (u & 0x80000000u) ? ~u : (u | 0x80000000u);
}
__device__ __forceinline__ float unmapf(unsigned k) {
    return (k & 0x80000000u) ? __uint_as_float(k ^ 0x80000000u)
                             : __uint_as_float(~k);
}

// identical val expression in both passes (explicit fmaf => bit-deterministic)
#define VAL(X, Y, Z, PS, Q) \
    fmaf((X), qx2[Q], fmaf((Y), qy2[Q], fmaf((Z), qz2[Q], (PS))))

#define PUSH(WQ, V, I)                                          \
    do {                                                        \
        int pos_ = atomicAdd(&s_cnt[WQ], 1);                    \
        if (pos_ < SCAP) {                                      \
            s_surv[((WQ)*SCAP + pos_) * 2] = (V);               \
            s_surv[((WQ)*SCAP + pos_) * 2 + 1] = __int_as_float(I); \
        }                                                       \
    } while (0)

// load one 4-point group (batch point index OO..OO+3) straight from L2.
// base = pc4 (fast: ps precomputed) or pc (fallback: ps computed inline).
#define LOADG(OO)                                                           \
    float4 x4 = *(const float4*)(base + (OO));                              \
    float4 y4 = *(const float4*)(base + NN + (OO));                         \
    float4 z4 = *(const float4*)(base + 2 * NN + (OO));                     \
    float4 p4;                                                              \
    if (usePS) {                                                            \
        p4 = *(const float4*)(base + 3 * NN + (OO));                        \
    } else {                                                                \
        p4.x = fmaf(x4.x, x4.x, fmaf(y4.x, y4.x, z4.x * z4.x));            \
        p4.y = fmaf(x4.y, x4.y, fmaf(y4.y, y4.y, z4.y * z4.y));            \
        p4.z = fmaf(x4.z, x4.z, fmaf(y4.z, y4.z, z4.z * z4.z));            \
        p4.w = fmaf(x4.w, x4.w, fmaf(y4.w, y4.w, z4.w * z4.w));            \
    }

__global__ __launch_bounds__(NTHR, 8) void soft_proj_kernel(
    const float* __restrict__ pc, const float* __restrict__ qc,
    const float* __restrict__ pf, const float* __restrict__ pfT,
    const float* __restrict__ pc4g, const float* __restrict__ temp,
    float* __restrict__ out, int useT, int usePS) {
    __shared__ __align__(16) float s_surv[QPB * SCAP * 2];  // 16384 B (val,idx)
    __shared__ int s_cnt[QPB];                              // 128 B
    __shared__ int s_sel[QPB * KK];                         // 2048 B
    __shared__ float s_thr[2 * QPB];                        // 256 B => ~18.8 KB

    const int bid = blockIdx.x;
    const int b = bid >> 7;               // 128 blocks per batch
    const int m0 = (bid & 127) * QPB;
    const int t = threadIdx.x;
    const int wave = t >> 6;              // 16 waves
    const int lane = t & 63;
    const int pairIdx = wave & 7;         // 8 wave-pairs x QPW=4 queries = 32
    const int half = wave >> 3;           // which point-half this wave scans

    const float* pcb = pc + (size_t)b * 3 * NN;
    const float* qcb = qc + (size_t)b * 3 * MM;
    const float* base = usePS ? pc4g + (size_t)b * 4 * NN : pcb;

    // scan-phase query constants: -2*q
    float qx2[QPW], qy2[QPW], qz2[QPW];
#pragma unroll
    for (int q = 0; q < QPW; ++q) {
        int m = m0 + pairIdx * QPW + q;
        qx2[q] = -2.0f * qcb[m];
        qy2[q] = -2.0f * qcb[MM + m];
        qz2[q] = -2.0f * qcb[2 * MM + m];
    }

    float mnA[QPW], mnB[QPW];
#pragma unroll
    for (int q = 0; q < QPW; ++q) { mnA[q] = 3.0e38f; mnB[q] = 3.0e38f; }

    // -------- pass A: per-lane min of val over 64 points, straight from L2 --
    // wave's half = [half*4096, half*4096+4096); lane covers 4 pts / iter.
    {
        const int ob = half * 4096 + lane * 4;
#pragma unroll 2
        for (int it = 0; it < 16; ++it) {
            int oo = ob + it * 256;
            LOADG(oo);
#pragma unroll
            for (int q = 0; q < QPW; ++q) {
                float v0 = VAL(x4.x, y4.x, z4.x, p4.x, q);
                float v1 = VAL(x4.y, y4.y, z4.y, p4.y, q);
                float v2 = VAL(x4.z, y4.z, z4.z, p4.z, q);
                float v3 = VAL(x4.w, y4.w, z4.w, p4.w, q);
                mnA[q] = min3f(v0, v1, mnA[q]);
                mnB[q] = min3f(v2, v3, mnB[q]);
            }
        }
    }

    // ---- per-wave radix select: 8th-smallest of 64 lane minima (per query) --
    // coarse: top 16 mapped bits; res|0xFFFF still a provable upper bound
    float thrv[QPW];
#pragma unroll
    for (int q = 0; q < QPW; ++q) {
        unsigned key = mapf(fminf(mnA[q], mnB[q]));
        unsigned res = 0u;
        for (int bb = 31; bb >= 16; --bb) {
            unsigned cand = res | (1u << bb);
            unsigned long long bal = __ballot(key < cand);
            int c2 = __popcll(bal);
            if (c2 < 8) res = cand;  // 8th smallest has this bit set
        }
        thrv[q] = unmapf(res | 0xFFFFu);  // upper bound on 8th smallest
    }
    if (lane == 0) {
#pragma unroll
        for (int q = 0; q < QPW; ++q)
            s_thr[half * QPB + pairIdx * QPW + q] = thrv[q];
    }
    if (t < QPB) s_cnt[t] = 0;
    __syncthreads();
    // t = max(tA8, tB8): >=8 points <= t in each half => >=16 total => valid
    // upper bound on the true 16th-smallest val.
#pragma unroll
    for (int q = 0; q < QPW; ++q)
        thrv[q] = fmaxf(s_thr[pairIdx * QPW + q], s_thr[QPB + pairIdx * QPW + q]);

    // -------- pass B: collect survivors val <= t, straight from L2 ----------
    {
        const int ob = half * 4096 + lane * 4;
#pragma unroll 2
        for (int it = 0; it < 16; ++it) {
            int oo = ob + it * 256;
            LOADG(oo);
#pragma unroll
            for (int q = 0; q < QPW; ++q) {
                float v0 = VAL(x4.x, y4.x, z4.x, p4.x, q);
                float v1 = VAL(x4.y, y4.y, z4.y, p4.y, q);
                float v2 = VAL(x4.z, y4.z, z4.z, p4.z, q);
                float v3 = VAL(x4.w, y4.w, z4.w, p4.w, q);
                // exact whole-group skip: min > t => every element > t
                if (fminf(min3f(v0, v1, v2), v3) <= thrv[q]) {
                    int wqq = pairIdx * QPW + q;
                    if (v0 <= thrv[q]) PUSH(wqq, v0, oo + 0);
                    if (v1 <= thrv[q]) PUSH(wqq, v1, oo + 1);
                    if (v2 <= thrv[q]) PUSH(wqq, v2, oo + 2);
                    if (v3 <= thrv[q]) PUSH(wqq, v3, oo + 3);
                }
            }
        }
    }
    __syncthreads();

    // ------------- exact select: rank survivors by (val, idx) ---------------
#pragma unroll
    for (int qq = 0; qq < 2; ++qq) {
        int wq = wave * 2 + qq;           // 16 waves x 2 = 32 queries
        int cnt = s_cnt[wq];
        cnt = __builtin_amdgcn_readfirstlane(cnt);
        if (cnt > SCAP) cnt = SCAP;
        bool valid = lane < cnt;
        float mv = 0.f;
        int mi = 0;
        if (valid) {
            mv = s_surv[(wq * SCAP + lane) * 2];
            mi = __float_as_int(s_surv[(wq * SCAP + lane) * 2 + 1]);
        }
        int rank = 0;
        for (int j = 0; j < cnt; ++j) {
            float vj = s_surv[(wq * SCAP + j) * 2];
            int ij = __float_as_int(s_surv[(wq * SCAP + j) * 2 + 1]);
            if (valid && (vj < mv || (vj == mv && ij < mi))) rank++;
        }
        if (valid && rank < KK) s_sel[wq * KK + rank] = mi;
    }
    __syncthreads();  // survivors dead; s_surv becomes the output stage

    // ---------------- softmax + gather + accumulate -------------------------
    float* stage = s_surv;  // [67 rows][STG=33 cols]
    float tval = temp[0];
    float sigma = fmaxf(tval * tval, 1.0e-4f);
    float inv_sigma = 1.0f / sigma;
    const float* pfTb = pfT + (size_t)b * NN * FF;
    const float* pfb = pf + (size_t)b * FF * NN;

#pragma unroll
    for (int qq = 0; qq < 2; ++qq) {
        int wq = wave * 2 + qq;
        int m = m0 + wq;
        float qxe = qcb[m], qye = qcb[MM + m], qze = qcb[2 * MM + m];
        int ik[KK];
        float dk[KK];
#pragma unroll
        for (int k = 0; k < KK; ++k) {
            int ii = __builtin_amdgcn_readfirstlane(s_sel[wq * KK + k]);
            ik[k] = ii;
            float px = pcb[ii], py = pcb[NN + ii], pz = pcb[2 * NN + ii];
            float dx = px - qxe, dy = py - qye, dz = pz - qze;
            dk[k] = fmaf(dx, dx, fmaf(dy, dy, dz * dz));  // exact direct form
        }
        float dmin = dk[0];
#pragma unroll
        for (int k = 1; k < KK; ++k) dmin = fminf(dmin, dk[k]);
        float ssum = 0.f, facc = 0.f, sx = 0.f, sy = 0.f, sz = 0.f;
#pragma unroll
        for (int k = 0; k < KK; ++k) {
            float e = __expf((dmin - dk[k]) * inv_sigma);
            ssum += e;
            float px = pcb[ik[k]], py = pcb[NN + ik[k]], pz = pcb[2 * NN + ik[k]];
            sx = fmaf(e, px, sx);
            sy = fmaf(e, py, sy);
            sz = fmaf(e, pz, sz);
            float fv = useT ? pfTb[(size_t)ik[k] * FF + lane]
                            : pfb[(size_t)lane * NN + ik[k]];
            facc = fmaf(e, fv, facc);
        }
        float rs = 1.0f / ssum;
        stage[lane * STG + wq] = facc * rs;
        if (lane == 0) {
            stage[(64) * STG + wq] = sx * rs;
            stage[(65) * STG + wq] = sy * rs;
            stage[(66) * STG + wq] = sz * rs;
        }
    }
    __syncthreads();

    // ---------------- coalesced write-out -----------------------------------
    const size_t featOff = (size_t)BB * 3 * MM;
    for (int j = t; j < 67 * QPB; j += NTHR) {
        int row = j >> 5, col = j & 31;
        float v = stage[row * STG + col];
        int m = m0 + col;
        if (row < 64)
            out[featOff + (size_t)b * FF * MM + (size_t)row * MM + m] = v;
        else
            out[(size_t)b * 3 * MM + (size_t)(row - 64) * MM + m] = v;
    }
}

extern "C" void kernel_launch(void* const* d_in, const int* in_sizes, int n_in,
                              void* d_out, int out_size, void* d_ws, size_t ws_size,
                              hipStream_t stream) {
    (void)in_sizes; (void)n_in; (void)out_size;
    const float* pc = (const float*)d_in[0];
    const float* qc = (const float*)d_in[1];
    const float* pf = (const float*)d_in[2];
    const float* temp = (const float*)d_in[3];
    float* out = (float*)d_out;
    float* pfT = (float*)d_ws;  // ws+0: 8MB (layout identical to R3/R5/R6)
    const size_t needT = (size_t)BB * NN * FF * sizeof(float);       // 8 MB
    const size_t needPS = (size_t)BB * 4 * NN * sizeof(float);       // 512 KB
    int useT = (ws_size >= needT && d_ws != nullptr) ? 1 : 0;
    int usePS = (ws_size >= needT + needPS && d_ws != nullptr) ? 1 : 0;
    float* pc4 = (float*)((char*)d_ws + needT);  // ws+8MB: 512KB

    if (useT || usePS) {
        hipLaunchKernelGGL(prep_kernel, dim3(NN / 64, BB), dim3(256), 0, stream,
                           pf, pfT, pc, pc4, useT, usePS);
    }
    hipLaunchKernelGGL(soft_proj_kernel, dim3((BB * MM) / QPB), dim3(NTHR), 0,
                       stream, pc, qc, pf, pfT, pc4, temp, out, useT, usePS);
}

// Round 9
// 118.925 us; speedup vs baseline: 1.0542x; 1.0542x over previous
//
#include <hip/hip_runtime.h>

// SoftProjection: B=4, N=8192 points, M=4096 queries, F=64 features, K=16 NN.
// R11: revert to the validated R5 scan structure (MFMA filter arc R8-R10
// falsified empirically: crash + 2 correctness fails insensitive to margin
// => structural, unfixable blind). R5 base (119.5us total / 58.3us main,
// VALUBusy 80%) plus only validated/epsilon-level changes:
//  - pass A mnA/mnB split with v_min3 (2 ops vs 4; correct in R6/R7 runs).
//  - pass B whole-group guard via min3 (2 ops vs 3; validated R6/R7).
//  - wave-parallel epilogue: lane k owns neighbor k (parallel dk, shfl_xor
//    tree for dmin/ssum/sx/sy/sz, 16-iter shfl+fma feature loop) replacing
//    the serial 16-step exp/gather chain; removes ik[16]/dk[16] reg arrays.
//    Only fp-reassociation-level output change (~1ulp; R5 absmax 3.9e-3 vs
//    threshold 6.7e-2).
// Structure (R3/R5): QPB=32, QPW=4 wave-pairs, 512 blocks x 1024 thr,
// LDS 49KB => 2 blocks/CU. Pass A: val = |p|^2 - 2 q.p per-lane min;
// per-wave radix/ballot (16-iter) 8th-smallest per half; t = max(halves)
// => >=16 pts <= t. Pass B: survivors val<=t (E~20, cap 54), exact rank by
// (val,idx). Epilogue recomputes exact direct-form d2 (matches reference).

#define BB 4
#define NN 8192
#define MM 4096
#define FF 64
#define KK 16
#define CHUNK 2048
#define NCHUNK 4
#define QPW 4
#define QPB 32
#define SCAP 54
#define NTHR 1024
#define STG 33

__device__ __forceinline__ float min3f(float a, float b, float c) {
    float d;
    asm("v_min3_f32 %0, %1, %2, %3" : "=v"(d) : "v"(a), "v"(b), "v"(c));
    return d;
}

__global__ __launch_bounds__(256) void transpose_feat(const float* __restrict__ pf,
                                                      float* __restrict__ pfT) {
    __shared__ float tile[64][65];
    const int b = blockIdx.y;
    const int n0 = blockIdx.x * 64;
    const int t = threadIdx.x;
    const int n = t & 63, fq = t >> 6;
#pragma unroll
    for (int i = 0; i < 16; ++i) {
        int f = fq * 16 + i;
        tile[f][n] = pf[(size_t)b * FF * NN + (size_t)f * NN + n0 + n];
    }
    __syncthreads();
    const int f2 = t & 63, nq = t >> 6;
#pragma unroll
    for (int i = 0; i < 16; ++i) {
        int nn2 = nq * 16 + i;
        pfT[(size_t)b * NN * FF + (size_t)(n0 + nn2) * FF + f2] = tile[f2][nn2];
    }
}

__device__ __forceinline__ unsigned mapf(float f) {
    unsigned u = __float_as_uint(f);
    return (u & 0x80000000u) ? ~u : (u | 0x80000000u);
}
__device__ __forceinline__ float unmapf(unsigned k) {
    return (k & 0x80000000u) ? __uint_as_float(k ^ 0x80000000u)
                             : __uint_as_float(~k);
}

// stage chunk C of point cloud into LDS: x, y, z, ps=|p|^2 (512 stager threads)
#define STAGE(C)                                                            \
    do {                                                                    \
        if (t < CHUNK / 4) {                                                \
            int base_ = (C)*CHUNK + t * 4;                                  \
            float4 x4_ = *(const float4*)(pcb + base_);                     \
            float4 y4_ = *(const float4*)(pcb + NN + base_);                \
            float4 z4_ = *(const float4*)(pcb + 2 * NN + base_);            \
            *(float4*)(s_pts + t * 4) = x4_;                                \
            *(float4*)(s_pts + CHUNK + t * 4) = y4_;                        \
            *(float4*)(s_pts + 2 * CHUNK + t * 4) = z4_;                    \
            float4 p4_;                                                     \
            p4_.x = fmaf(x4_.x, x4_.x, fmaf(y4_.x, y4_.x, z4_.x * z4_.x));  \
            p4_.y = fmaf(x4_.y, x4_.y, fmaf(y4_.y, y4_.y, z4_.y * z4_.y));  \
            p4_.z = fmaf(x4_.z, x4_.z, fmaf(y4_.z, y4_.z, z4_.z * z4_.z));  \
            p4_.w = fmaf(x4_.w, x4_.w, fmaf(y4_.w, y4_.w, z4_.w * z4_.w));  \
            *(float4*)(s_pts + 3 * CHUNK + t * 4) = p4_;                    \
        }                                                                   \
    } while (0)

// identical val expression in both passes (explicit fmaf => bit-deterministic)
#define VAL(X, Y, Z, PS, Q) \
    fmaf((X), qx2[Q], fmaf((Y), qy2[Q], fmaf((Z), qz2[Q], (PS))))

#define PUSH(WQ, V, I)                                          \
    do {                                                        \
        int pos_ = atomicAdd(&s_cnt[WQ], 1);                    \
        if (pos_ < SCAP) {                                      \
            s_surv[((WQ)*SCAP + pos_) * 2] = (V);               \
            s_surv[((WQ)*SCAP + pos_) * 2 + 1] = __int_as_float(I); \
        }                                                       \
    } while (0)

__global__ __launch_bounds__(NTHR, 8) void soft_proj_kernel(
    const float* __restrict__ pc, const float* __restrict__ qc,
    const float* __restrict__ pf, const float* __restrict__ pfT,
    const float* __restrict__ temp, float* __restrict__ out, int useT) {
    __shared__ __align__(16) float s_pts[4 * CHUNK];        // 32768 B
    __shared__ __align__(16) float s_surv[QPB * SCAP * 2];  // 13824 B (val,idx)
    __shared__ int s_cnt[QPB];                              // 128 B
    __shared__ int s_sel[QPB * KK];                         // 2048 B
    __shared__ float s_thr[2 * QPB];                        // 256 B => 49024 B

    const int bid = blockIdx.x;
    const int b = bid >> 7;               // 128 blocks per batch
    const int m0 = (bid & 127) * QPB;
    const int t = threadIdx.x;
    const int wave = t >> 6;              // 16 waves
    const int lane = t & 63;
    const int pairIdx = wave & 7;         // 8 wave-pairs x QPW=4 queries = 32
    const int half = wave >> 3;           // which point-half this wave scans

    const float* pcb = pc + (size_t)b * 3 * NN;
    const float* qcb = qc + (size_t)b * 3 * MM;

    // scan-phase query constants: -2*q
    float qx2[QPW], qy2[QPW], qz2[QPW];
#pragma unroll
    for (int q = 0; q < QPW; ++q) {
        int m = m0 + pairIdx * QPW + q;
        qx2[q] = -2.0f * qcb[m];
        qy2[q] = -2.0f * qcb[MM + m];
        qz2[q] = -2.0f * qcb[2 * MM + m];
    }

    float mnA[QPW], mnB[QPW];
#pragma unroll
    for (int q = 0; q < QPW; ++q) { mnA[q] = 3.0e38f; mnB[q] = 3.0e38f; }

    // ---------------- pass A: per-lane min of val over 64 points ------------
    for (int c = 0; c < NCHUNK; ++c) {
        __syncthreads();
        STAGE(c);
        __syncthreads();
        const int ob = half * 1024 + lane * 4;
#pragma unroll
        for (int g = 0; g < 4; ++g) {
            int oo = ob + g * 256;
            float4 x4 = *(const float4*)(s_pts + oo);
            float4 y4 = *(const float4*)(s_pts + CHUNK + oo);
            float4 z4 = *(const float4*)(s_pts + 2 * CHUNK + oo);
            float4 p4 = *(const float4*)(s_pts + 3 * CHUNK + oo);
#pragma unroll
            for (int q = 0; q < QPW; ++q) {
                float v0 = VAL(x4.x, y4.x, z4.x, p4.x, q);
                float v1 = VAL(x4.y, y4.y, z4.y, p4.y, q);
                float v2 = VAL(x4.z, y4.z, z4.z, p4.z, q);
                float v3 = VAL(x4.w, y4.w, z4.w, p4.w, q);
                mnA[q] = min3f(v0, v1, mnA[q]);
                mnB[q] = min3f(v2, v3, mnB[q]);
            }
        }
    }

    // ---- per-wave radix select: 8th-smallest of 64 lane minima (per query) --
    // coarse: top 16 mapped bits; res|0xFFFF still a provable upper bound
    float thrv[QPW];
#pragma unroll
    for (int q = 0; q < QPW; ++q) {
        unsigned key = mapf(fminf(mnA[q], mnB[q]));
        unsigned res = 0u;
        for (int bb = 31; bb >= 16; --bb) {
            unsigned cand = res | (1u << bb);
            unsigned long long bal = __ballot(key < cand);
            int c2 = __popcll(bal);
            if (c2 < 8) res = cand;  // 8th smallest has this bit set
        }
        thrv[q] = unmapf(res | 0xFFFFu);  // upper bound on 8th smallest
    }
    if (lane == 0) {
#pragma unroll
        for (int q = 0; q < QPW; ++q)
            s_thr[half * QPB + pairIdx * QPW + q] = thrv[q];
    }
    if (t < QPB) s_cnt[t] = 0;
    __syncthreads();
    // t = max(tA8, tB8): >=8 points <= t in each half => >=16 total => valid
    // upper bound on the true 16th-smallest val.
#pragma unroll
    for (int q = 0; q < QPW; ++q)
        thrv[q] = fmaxf(s_thr[pairIdx * QPW + q], s_thr[QPB + pairIdx * QPW + q]);

    // ---------------- pass B: collect survivors val <= t --------------------
    for (int c = 0; c < NCHUNK; ++c) {
        __syncthreads();
        STAGE(c);
        __syncthreads();
        const int ob = half * 1024 + lane * 4;
#pragma unroll
        for (int g = 0; g < 4; ++g) {
            int oo = ob + g * 256;
            float4 x4 = *(const float4*)(s_pts + oo);
            float4 y4 = *(const float4*)(s_pts + CHUNK + oo);
            float4 z4 = *(const float4*)(s_pts + 2 * CHUNK + oo);
            float4 p4 = *(const float4*)(s_pts + 3 * CHUNK + oo);
            int gi = c * CHUNK + oo;
#pragma unroll
            for (int q = 0; q < QPW; ++q) {
                float v0 = VAL(x4.x, y4.x, z4.x, p4.x, q);
                float v1 = VAL(x4.y, y4.y, z4.y, p4.y, q);
                float v2 = VAL(x4.z, y4.z, z4.z, p4.z, q);
                float v3 = VAL(x4.w, y4.w, z4.w, p4.w, q);
                // exact whole-group skip: min > t => every element > t
                if (fminf(min3f(v0, v1, v2), v3) <= thrv[q]) {
                    int wqq = pairIdx * QPW + q;
                    if (v0 <= thrv[q]) PUSH(wqq, v0, gi + 0);
                    if (v1 <= thrv[q]) PUSH(wqq, v1, gi + 1);
                    if (v2 <= thrv[q]) PUSH(wqq, v2, gi + 2);
                    if (v3 <= thrv[q]) PUSH(wqq, v3, gi + 3);
                }
            }
        }
    }
    __syncthreads();

    // ------------- exact select: rank survivors by (val, idx) ---------------
#pragma unroll
    for (int qq = 0; qq < 2; ++qq) {
        int wq = wave * 2 + qq;           // 16 waves x 2 = 32 queries
        int cnt = s_cnt[wq];
        cnt = __builtin_amdgcn_readfirstlane(cnt);
        if (cnt > SCAP) cnt = SCAP;
        bool valid = lane < cnt;
        float mv = 0.f;
        int mi = 0;
        if (valid) {
            mv = s_surv[(wq * SCAP + lane) * 2];
            mi = __float_as_int(s_surv[(wq * SCAP + lane) * 2 + 1]);
        }
        int rank = 0;
        for (int j = 0; j < cnt; ++j) {
            float vj = s_surv[(wq * SCAP + j) * 2];
            int ij = __float_as_int(s_surv[(wq * SCAP + j) * 2 + 1]);
            if (valid && (vj < mv || (vj == mv && ij < mi))) rank++;
        }
        if (valid && rank < KK) s_sel[wq * KK + rank] = mi;
    }
    __syncthreads();  // survivors dead; s_surv becomes the output stage

    // -------- softmax + gather, wave-parallel: lane k owns neighbor k -------
    float* stage = s_surv;  // [67 rows][STG=33 cols]
    float tval = temp[0];
    float sigma = fmaxf(tval * tval, 1.0e-4f);
    float inv_sigma = 1.0f / sigma;
    const float* pfTb = pfT + (size_t)b * NN * FF;
    const float* pfb = pf + (size_t)b * FF * NN;

#pragma unroll
    for (int qq = 0; qq < 2; ++qq) {
        int wq = wave * 2 + qq;
        int m = m0 + wq;
        float qxe = qcb[m], qye = qcb[MM + m], qze = qcb[2 * MM + m];
        // every 16-lane group loads the same 16 neighbors (lane&15)
        int ik = s_sel[wq * KK + (lane & 15)];
        float px = pcb[ik], py = pcb[NN + ik], pz = pcb[2 * NN + ik];
        float dx = px - qxe, dy = py - qye, dz = pz - qze;
        float dk = fmaf(dx, dx, fmaf(dy, dy, dz * dz));  // exact direct form
        float dmin = dk;
#pragma unroll
        for (int s = 1; s < 16; s <<= 1) dmin = fminf(dmin, __shfl_xor(dmin, s));
        float e = __expf((dmin - dk) * inv_sigma);
        float ssum = e;
#pragma unroll
        for (int s = 1; s < 16; s <<= 1) ssum += __shfl_xor(ssum, s);
        float w = e * (1.0f / ssum);
        float sx = w * px, sy = w * py, sz = w * pz;
#pragma unroll
        for (int s = 1; s < 16; s <<= 1) {
            sx += __shfl_xor(sx, s);
            sy += __shfl_xor(sy, s);
            sz += __shfl_xor(sz, s);
        }
        // features: all 64 lanes, f = lane; weights broadcast from lanes 0-15
        float facc = 0.f;
#pragma unroll
        for (int k = 0; k < KK; ++k) {
            float wk = __shfl(w, k);
            int iik = __shfl(ik, k);
            float fv = useT ? pfTb[(size_t)iik * FF + lane]
                            : pfb[(size_t)lane * NN + iik];
            facc = fmaf(wk, fv, facc);
        }
        stage[lane * STG + wq] = facc;
        if (lane == 0) {
            stage[(64) * STG + wq] = sx;
            stage[(65) * STG + wq] = sy;
            stage[(66) * STG + wq] = sz;
        }
    }
    __syncthreads();

    // ---------------- coalesced write-out -----------------------------------
    const size_t featOff = (size_t)BB * 3 * MM;
    for (int j = t; j < 67 * QPB; j += NTHR) {
        int row = j >> 5, col = j & 31;
        float v = stage[row * STG + col];
        int m = m0 + col;
        if (row < 64)
            out[featOff + (size_t)b * FF * MM + (size_t)row * MM + m] = v;
        else
            out[(size_t)b * 3 * MM + (size_t)(row - 64) * MM + m] = v;
    }
}

extern "C" void kernel_launch(void* const* d_in, const int* in_sizes, int n_in,
                              void* d_out, int out_size, void* d_ws, size_t ws_size,
                              hipStream_t stream) {
    (void)in_sizes; (void)n_in; (void)out_size;
    const float* pc = (const float*)d_in[0];
    const float* qc = (const float*)d_in[1];
    const float* pf = (const float*)d_in[2];
    const float* temp = (const float*)d_in[3];
    float* out = (float*)d_out;
    float* pfT = (float*)d_ws;
    const size_t needT = (size_t)BB * NN * FF * sizeof(float);  // 8 MB
    int useT = (ws_size >= needT && d_ws != nullptr) ? 1 : 0;

    if (useT) {
        hipLaunchKernelGGL(transpose_feat, dim3(NN / 64, BB), dim3(256), 0, stream,
                           pf, pfT);
    }
    hipLaunchKernelGGL(soft_proj_kernel, dim3((BB * MM) / QPB), dim3(NTHR), 0,
                       stream, pc, qc, pf, pfT, temp, out, useT);
}